// Round 11
// baseline (15.239 us; speedup 1.0000x reference)
//
#include <hip/hip_runtime.h>

#define B_TOTAL 4096
#define D 32
#define H 256
#define SPB 16           // samples per block (= MFMA M/N)
#define NW 16            // waves per block (1024 threads -> 4 waves/SIMD)
#define HPW 16           // hidden units per wave
#define PGS 34           // partG row stride (dwords)
#define XCS 40           // xcH/xcL row stride (u16)

static constexpr float EPS = 0.1f;

typedef __attribute__((ext_vector_type(8))) short short8v;   // 8 x bf16
typedef __attribute__((ext_vector_type(4))) float f32x4;

__device__ __forceinline__ unsigned short bf16rne(float f) {
  unsigned u = __float_as_uint(f);
  u += 0x7FFFu + ((u >> 16) & 1u);
  return (unsigned short)(u >> 16);
}
__device__ __forceinline__ float fromb(unsigned short h) {
  return __uint_as_float(((unsigned)h) << 16);
}
__device__ __forceinline__ void split_rne(float f, unsigned short& hi, unsigned short& lo) {
  hi = bf16rne(f); lo = bf16rne(f - fromb(hi));
}

#define MFMA16(A, Bf, C) __builtin_amdgcn_mfma_f32_16x16x32_bf16((A), (Bf), (C), 0, 0, 0)

// k-permutations (MFMA contracts K in any order as long as A and B agree):
//   kappa(lg*8+j) = lg*4 + (j>>1) + ((j&1)<<4)   [z-pass k=d; matches xc pair layout]
//   g-pass k-slot lg*8+j: j<4 -> h_local = lg*4+j, j>=4 -> zero (k half-filled, HPW=16)

__global__ __launch_bounds__(1024, 4) void ma_flow_kernel(
    const float* __restrict__ x_in, const float* __restrict__ logp_in,
    const float* __restrict__ w1, const float* __restrict__ b1,
    const float* __restrict__ w2, float* __restrict__ out)
{
  __shared__ __align__(16) float partG[NW][SPB][PGS];        // per-wave partial g
  __shared__ __align__(16) unsigned short xcH[SPB][XCS];     // xc hi-bf16, pair layout
  __shared__ __align__(16) unsigned short xcL[SPB][XCS];     // xc lo-bf16, pair layout

  const int tid = threadIdx.x;
  const int l  = tid & 63;
  const int wv = tid >> 6;       // wave id = 16-h slice (0..15)
  const int lr = l & 15;         // MFMA index lane: sample (z-out/g-A); d-col (Bg)
  const int lg = l >> 4;         // MFMA k-group
  const int hbase = wv * HPW;
  const int s_own = tid >> 5;    // owned sample (tid<512)
  const int d_own = tid & 31;    // owned dim
  const int xci = ((d_own & 15) << 1) | (d_own >> 4);  // u16 index in pair layout

  // ---------------- weight fragments (registers) --------------------------------
  // z-pass A=w1: A[m=h][k=d], h = hbase + lr, k gathered in kappa order
  short8v Bzh, Bzl;
  float cpart = 0.0f;
  {
    short8v hi, lo;
#pragma unroll
    for (int j = 0; j < 8; ++j) {
      const int dj = lg * 4 + (j >> 1) + ((j & 1) << 4);   // kappa
      float w = w1[dj * H + hbase + lr];
      cpart = fmaf(w, w, cpart);
      unsigned short hb, lb; split_rne(w, hb, lb);
      hi[j] = (short)hb; lo[j] = (short)lb;
    }
    Bzh = hi; Bzl = lo;
    cpart += __shfl_xor(cpart, 16);            // sum the 4 k-groups -> c_h (h by lr)
    cpart += __shfl_xor(cpart, 32);
  }
  // per-lane h-tables for the swapped z output: h = hbase + lg*4 + r
  f32x4 b1v, w2v, w2cv;
#pragma unroll
  for (int r = 0; r < 4; ++r) {
    const int hh = hbase + lg * 4 + r;
    b1v[r] = b1[hh];
    float w2x = w2[hh];
    w2v[r] = w2x;
    w2cv[r] = w2x * __shfl(cpart, lg * 4 + r);  // c redistributed lr->(lg,r)
  }
  // g-pass B=w1^T: B[k=h_local][n=d], d = nu*16 + lr; k-slots j>=4 zeroed
  short8v Bgh[2], Bgl[2];
#pragma unroll
  for (int nu = 0; nu < 2; ++nu) {
    const int d = nu * 16 + lr;
    short8v hi, lo;
#pragma unroll
    for (int j = 0; j < 8; ++j) {
      if (j < 4) {
        float w = w1[d * H + hbase + lg * 4 + j];
        unsigned short hb, lb; split_rne(w, hb, lb);
        hi[j] = (short)hb; lo[j] = (short)lb;
      } else {
        hi[j] = 0; lo[j] = 0;
      }
    }
    Bgh[nu] = hi; Bgl[nu] = lo;
  }

  // ---------------- state init: thread owns (s_own, d_own) for tid<512 ----------
  float x0r = 0.0f, accr = 0.0f, lp = 0.0f;
  if (tid < SPB * D) {
    x0r = x_in[blockIdx.x * (SPB * D) + tid];   // coalesced
    unsigned u = __float_as_uint(x0r);
    xcH[s_own][xci] = (unsigned short)(u >> 16);
    float res = x0r - __uint_as_float(u & 0xFFFF0000u);   // exact
    xcL[s_own][xci] = (unsigned short)(__float_as_uint(res) >> 16);
  }
  if (tid < SPB) lp = logp_in[blockIdx.x * SPB + tid];
  float lapAcc = 0.0f;     // wa-weighted lap partial (this lane's 4 h's, sample lr)
  __syncthreads();

  // ---------------- 8 RK4 stage evaluations -------------------------------------
#pragma unroll 1
  for (int stage = 0; stage < 8; ++stage) {
    const int st = stage & 3;
    const float wa = (st == 0 || st == 3) ? (EPS / 6.0f) : (EPS / 3.0f);
    const float wc = (st == 2) ? EPS : (EPS * 0.5f);

    // -- phase 1: swapped z-MFMAs (D[m=h][n=sample]) + sigmoid, in-register -----
    short8v xh = *reinterpret_cast<const short8v*>(&xcH[lr][lg * 8]);
    short8v xl = *reinterpret_cast<const short8v*>(&xcL[lr][lg * 8]);

    f32x4 z = MFMA16(Bzh, xh, b1v);   // A=w1 (m=h), B=xc (n=sample)
    z = MFMA16(Bzh, xl, z);
    z = MFMA16(Bzl, xh, z);

    float q = 0.0f;
    unsigned short ab[4];
#pragma unroll
    for (int r = 0; r < 4; ++r) {
      float E = __expf(-z[r]);
      float t = __builtin_amdgcn_rcpf(1.0f + E);          // sigmoid
      q = fmaf(t * t * E, w2cv[r], q);                    // s(1-s) * w2*c
      ab[r] = bf16rne(t * w2v[r]);                        // a = s*w2 (bf16)
    }
    lapAcc = fmaf(wa, q, lapAcc);
    short8v aF;                                           // k-slots j>=4 zero
#pragma unroll
    for (int j = 0; j < 8; ++j) aF[j] = (j < 4) ? (short)ab[j] : (short)0;

    // -- phase 2: g-MFMAs straight from registers, partG write ------------------
#pragma unroll
    for (int nu = 0; nu < 2; ++nu) {
      f32x4 g = {0.0f, 0.0f, 0.0f, 0.0f};
      g = MFMA16(aF, Bgh[nu], g);
      g = MFMA16(aF, Bgl[nu], g);
#pragma unroll
      for (int r = 0; r < 4; ++r)
        partG[wv][lg * 4 + r][nu * 16 + lr] = g[r];
    }
    __syncthreads();                     // barrier 1: partG ready

    // -- phase 3: owner-thread reduce (16 partials), state update ---------------
    if (tid < SPB * D) {
      float ps[NW];
#pragma unroll
      for (int w = 0; w < NW; ++w) ps[w] = partG[w][s_own][d_own];
      float gsum = (((ps[0] + ps[1]) + (ps[2] + ps[3])) + ((ps[4] + ps[5]) + (ps[6] + ps[7])))
                 + (((ps[8] + ps[9]) + (ps[10] + ps[11])) + ((ps[12] + ps[13]) + (ps[14] + ps[15])));
      accr = fmaf(wa, gsum, accr);
      float xw;
      if (st < 3) {
        xw = fmaf(wc, gsum, x0r);
      } else {
        x0r += accr; accr = 0.0f; xw = x0r;
      }
      unsigned u = __float_as_uint(xw);
      xcH[s_own][xci] = (unsigned short)(u >> 16);
      float res = xw - __uint_as_float(u & 0xFFFF0000u);    // exact
      xcL[s_own][xci] = (unsigned short)(__float_as_uint(res) >> 16);
    }
    __syncthreads();                     // barrier 2: xc ready (+ partG WAR)
  }

  // ---------------- final laplacian reduce (once) --------------------------------
  lapAcc += __shfl_xor(lapAcc, 16);      // sum over the 4 lg groups
  lapAcc += __shfl_xor(lapAcc, 32);
  if (l < 16) partG[wv][lr][0] = lapAcc; // per-wave partial for sample lr
  __syncthreads();

  // ---------------- output --------------------------------------------------------
  if (tid < SPB * D) out[blockIdx.x * (SPB * D) + tid] = x0r;   // coalesced
  if (tid < SPB) {
    float lt = 0.0f;
#pragma unroll
    for (int w = 0; w < NW; ++w) lt += partG[w][tid][0];
    out[B_TOTAL * D + blockIdx.x * SPB + tid] = lp - lt;
  }
}

extern "C" void kernel_launch(void* const* d_in, const int* in_sizes, int n_in,
                              void* d_out, int out_size, void* d_ws, size_t ws_size,
                              hipStream_t stream) {
  const float* x    = (const float*)d_in[0];
  const float* logp = (const float*)d_in[1];
  const float* w1   = (const float*)d_in[2];
  const float* b1   = (const float*)d_in[3];
  const float* w2   = (const float*)d_in[4];
  // d_in[5] (b2) shifts u only; it does not affect grad_u or the laplacian.
  float* out = (float*)d_out;

  ma_flow_kernel<<<B_TOTAL / SPB, 1024, 0, stream>>>(x, logp, w1, b1, w2, out);
}